// Round 16
// baseline (561.176 us; speedup 1.0000x reference)
//
#include <hip/hip_runtime.h>

typedef _Float16 f16;
typedef _Float16 f16x8 __attribute__((ext_vector_type(8)));
typedef _Float16 f16x4 __attribute__((ext_vector_type(4)));
typedef float f32x4 __attribute__((ext_vector_type(4)));
typedef float fv4 __attribute__((ext_vector_type(4)));

#define BN_EPS 1e-5f

constexpr int EPI_RAW = 0;         // write fp32 C (no transform)       [sim]
constexpr int EPI_HALF_NORM = 2;   // BN+ReLU -> fp16 + ROW norm2       [Q,K]
constexpr int EPI_HALF = 3;        // fp16 C (no transform)             [wv]
constexpr int EPI_BN_F32 = 4;      // BN+ReLU -> fp32 C                 [f]
constexpr int EPI_HALF_NORM_T = 5; // BN(row)+ReLU -> fp16 + COL norm2  [V^T]

__device__ __forceinline__ void gload_lds16(const void* g, void* l) {
  __builtin_amdgcn_global_load_lds(
      (const __attribute__((address_space(1))) unsigned int*)g,
      (__attribute__((address_space(3))) unsigned int*)l, 16, 0, 0);
}

// ================================================================= gemm8
// R12-verified kernel (K/V ~157 us @ 40% MfmaUtil). 256x256 tile, BK=64,
// 8 waves (2Mx4N), 8-phase / 1-barrier-per-phase / counted-vmcnt,
// cross-phase register prefetch with named frags. FROZEN.
#define LDSA(d0, d1, d2, d3, par, kk, mi0)            \
  {                                                   \
    const int ab_ = (par)*65536 + (kk)*16384 + aoff;  \
    d0 = ldf(ab_ + (((mi0) + 0) << 10));              \
    d1 = ldf(ab_ + (((mi0) + 1) << 10));              \
    d2 = ldf(ab_ + (((mi0) + 2) << 10));              \
    d3 = ldf(ab_ + (((mi0) + 3) << 10));              \
  }
#define LDSB(d0, d1, d2, d3, par, kk)                 \
  {                                                   \
    const int bb_ = (par)*65536 + (kk)*16384 + boff;  \
    d0 = ldf(bb_ + (0 << 10));                        \
    d1 = ldf(bb_ + (1 << 10));                        \
    d2 = ldf(bb_ + (2 << 10));                        \
    d3 = ldf(bb_ + (3 << 10));                        \
  }
#define MM16(a0, a1, a2, a3, b0, b1, b2, b3, mi0)                              \
  __builtin_amdgcn_s_setprio(1);                                               \
  acc[(mi0) + 0][0] = __builtin_amdgcn_mfma_f32_16x16x32_f16(a0, b0, acc[(mi0) + 0][0], 0, 0, 0); \
  acc[(mi0) + 0][1] = __builtin_amdgcn_mfma_f32_16x16x32_f16(a0, b1, acc[(mi0) + 0][1], 0, 0, 0); \
  acc[(mi0) + 0][2] = __builtin_amdgcn_mfma_f32_16x16x32_f16(a0, b2, acc[(mi0) + 0][2], 0, 0, 0); \
  acc[(mi0) + 0][3] = __builtin_amdgcn_mfma_f32_16x16x32_f16(a0, b3, acc[(mi0) + 0][3], 0, 0, 0); \
  acc[(mi0) + 1][0] = __builtin_amdgcn_mfma_f32_16x16x32_f16(a1, b0, acc[(mi0) + 1][0], 0, 0, 0); \
  acc[(mi0) + 1][1] = __builtin_amdgcn_mfma_f32_16x16x32_f16(a1, b1, acc[(mi0) + 1][1], 0, 0, 0); \
  acc[(mi0) + 1][2] = __builtin_amdgcn_mfma_f32_16x16x32_f16(a1, b2, acc[(mi0) + 1][2], 0, 0, 0); \
  acc[(mi0) + 1][3] = __builtin_amdgcn_mfma_f32_16x16x32_f16(a1, b3, acc[(mi0) + 1][3], 0, 0, 0); \
  acc[(mi0) + 2][0] = __builtin_amdgcn_mfma_f32_16x16x32_f16(a2, b0, acc[(mi0) + 2][0], 0, 0, 0); \
  acc[(mi0) + 2][1] = __builtin_amdgcn_mfma_f32_16x16x32_f16(a2, b1, acc[(mi0) + 2][1], 0, 0, 0); \
  acc[(mi0) + 2][2] = __builtin_amdgcn_mfma_f32_16x16x32_f16(a2, b2, acc[(mi0) + 2][2], 0, 0, 0); \
  acc[(mi0) + 2][3] = __builtin_amdgcn_mfma_f32_16x16x32_f16(a2, b3, acc[(mi0) + 2][3], 0, 0, 0); \
  acc[(mi0) + 3][0] = __builtin_amdgcn_mfma_f32_16x16x32_f16(a3, b0, acc[(mi0) + 3][0], 0, 0, 0); \
  acc[(mi0) + 3][1] = __builtin_amdgcn_mfma_f32_16x16x32_f16(a3, b1, acc[(mi0) + 3][1], 0, 0, 0); \
  acc[(mi0) + 3][2] = __builtin_amdgcn_mfma_f32_16x16x32_f16(a3, b2, acc[(mi0) + 3][2], 0, 0, 0); \
  acc[(mi0) + 3][3] = __builtin_amdgcn_mfma_f32_16x16x32_f16(a3, b3, acc[(mi0) + 3][3], 0, 0, 0); \
  __builtin_amdgcn_s_setprio(0);

template <int EPI>
__global__ __launch_bounds__(512, 1) void gemm8_kernel(
    const f16* __restrict__ A, const f16* __restrict__ Bh, int N, int K,
    int gx, f16* __restrict__ Ch, const float* __restrict__ bias,
    const float* __restrict__ gamma, const float* __restrict__ beta,
    const float* __restrict__ mean, const float* __restrict__ var,
    float* __restrict__ norm2) {
  __shared__ __align__(16) char smem[131072];

  const int nwg = gridDim.x;
  const int bid = blockIdx.x;
  const int swz = (bid & 7) * (nwg >> 3) + (bid >> 3);  // XCD swizzle (nwg%8==0)
  const int brow = (swz / gx) * 256;
  const int bcol = (swz % gx) * 256;

  const int tid = threadIdx.x;
  const int lane = tid & 63;
  const int w = tid >> 6;
  const int wm = w >> 2;     // 0..1
  const int wn = w & 3;      // 0..3
  const int l15 = lane & 15;
  const int l4 = lane >> 4;  // kslot 0..3

  const int NT = K >> 6;

  // staging: source chunk permutation (slot-xor within row), coalesced rows
  const int c0 = tid ^ ((tid >> 3) & 3);
  const int srow = c0 >> 2;     // 0..127 (second chunk: +128)
  const int sk = (c0 & 3) * 8;  // element offset within 32-k row
  const size_t gA0 = (size_t)(brow + srow) * K + sk;
  const size_t gB0 = (size_t)(bcol + srow) * K + sk;
  const size_t gstep = (size_t)128 * K;
  char* const ldst = smem + tid * 16;

  auto STAGE = [&](int v, int par, int op, int kk) {
    if (v >= NT) return;
    const int k0 = v * 64 + kk * 32;
    const f16* g = (op == 0) ? (A + gA0 + k0) : (Bh + gB0 + k0);
    char* l = ldst + par * 65536 + op * 32768 + kk * 16384;
    gload_lds16(g, l);
    gload_lds16(g + gstep, l + 8192);
  };

  f32x4 acc[8][4] = {};

  // fragment read swizzle + per-thread bases (byte offsets within piece)
  const int kx16 = (l4 ^ ((l15 >> 1) & 3)) * 16;
  const int aoff = ((wm * 128 + l15) << 6) + kx16;
  const int boff = 32768 + ((wn * 64 + l15) << 6) + kx16;

  auto ldf = [&](int off) -> f16x8 { return *(const f16x8*)(smem + off); };
  auto BAR = [&]() { __builtin_amdgcn_s_barrier(); };
  auto VMID = [&](int tcur) {
    if (tcur + 2 >= NT)
      asm volatile("s_waitcnt vmcnt(0)" ::: "memory");
    else
      asm volatile("s_waitcnt vmcnt(4)" ::: "memory");
  };
  auto VEND = [&](int tcur) {
    if (tcur + 2 < NT) asm volatile("s_waitcnt vmcnt(4)" ::: "memory");
  };

  f16x8 aX0, aX1, aX2, aX3, aY0, aY1, aY2, aY3;
  f16x8 bX0, bX1, bX2, bX3, bY0, bY1, bY2, bY3;

  // prologue: tile0 fully + tile1.k0 halves (6 events, 12 loads)
  STAGE(0, 0, 0, 0);
  STAGE(0, 0, 1, 0);
  STAGE(0, 0, 0, 1);
  STAGE(0, 0, 1, 1);
  STAGE(1, 1, 0, 0);
  STAGE(1, 1, 1, 0);
  asm volatile("s_waitcnt vmcnt(4)" ::: "memory");
  __builtin_amdgcn_s_barrier();

  // initial fragments for P1 (buf0.k0)
  LDSA(aX0, aX1, aX2, aX3, 0, 0, 0);
  LDSB(bX0, bX1, bX2, bX3, 0, 0);

  for (int t = 0; t < NT; t += 2) {
    STAGE(t + 1, 1, 0, 1);
    MM16(aX0, aX1, aX2, aX3, bX0, bX1, bX2, bX3, 0);
    LDSA(aY0, aY1, aY2, aY3, 0, 0, 4);
    BAR();
    STAGE(t + 1, 1, 1, 1);
    MM16(aY0, aY1, aY2, aY3, bX0, bX1, bX2, bX3, 4);
    LDSA(aX0, aX1, aX2, aX3, 0, 1, 0);
    LDSB(bY0, bY1, bY2, bY3, 0, 1);
    BAR();
    STAGE(t + 2, 0, 0, 0);
    MM16(aX0, aX1, aX2, aX3, bY0, bY1, bY2, bY3, 0);
    LDSA(aY0, aY1, aY2, aY3, 0, 1, 4);
    BAR();
    STAGE(t + 2, 0, 1, 0);
    VMID(t);
    MM16(aY0, aY1, aY2, aY3, bY0, bY1, bY2, bY3, 4);
    LDSA(aX0, aX1, aX2, aX3, 1, 0, 0);
    LDSB(bX0, bX1, bX2, bX3, 1, 0);
    BAR();
    STAGE(t + 2, 0, 0, 1);
    MM16(aX0, aX1, aX2, aX3, bX0, bX1, bX2, bX3, 0);
    LDSA(aY0, aY1, aY2, aY3, 1, 0, 4);
    BAR();
    STAGE(t + 2, 0, 1, 1);
    MM16(aY0, aY1, aY2, aY3, bX0, bX1, bX2, bX3, 4);
    LDSA(aX0, aX1, aX2, aX3, 1, 1, 0);
    LDSB(bY0, bY1, bY2, bY3, 1, 1);
    BAR();
    STAGE(t + 3, 1, 0, 0);
    MM16(aX0, aX1, aX2, aX3, bY0, bY1, bY2, bY3, 0);
    LDSA(aY0, aY1, aY2, aY3, 1, 1, 4);
    BAR();
    STAGE(t + 3, 1, 1, 0);
    VEND(t);
    MM16(aY0, aY1, aY2, aY3, bY0, bY1, bY2, bY3, 4);
    LDSA(aX0, aX1, aX2, aX3, 0, 0, 0);
    LDSB(bX0, bX1, bX2, bX3, 0, 0);
    BAR();
  }

  // epilogue: C/D layout col=lane&15, row=(lane>>4)*4+j
  if constexpr (EPI == EPI_HALF_NORM_T) {
    float colsum[4] = {0.f, 0.f, 0.f, 0.f};
#pragma unroll
    for (int mi = 0; mi < 8; ++mi) {
#pragma unroll
      for (int jj = 0; jj < 4; ++jj) {
        const int grow = brow + wm * 128 + mi * 16 + l4 * 4 + jj;  // d index
        const float bb = bias[grow], gg = gamma[grow], mm = mean[grow];
        const float vv = var[grow], be = beta[grow];
#pragma unroll
        for (int ni = 0; ni < 4; ++ni) {
          const int gcol = bcol + wn * 64 + ni * 16 + l15;
          float y = fmaxf(acc[mi][ni][jj] + bb, 0.0f);
          y = gg * (y - mm) / sqrtf(vv + BN_EPS) + be;
          Ch[(size_t)grow * N + gcol] = (f16)y;
          colsum[ni] += y * y;
        }
      }
    }
#pragma unroll
    for (int ni = 0; ni < 4; ++ni) {
      float s = colsum[ni];
      s += __shfl_xor(s, 16);
      s += __shfl_xor(s, 32);
      if (l4 == 0)
        atomicAdd(&norm2[bcol + wn * 64 + ni * 16 + l15], s);
    }
  } else {
#pragma unroll
    for (int mi = 0; mi < 8; ++mi) {
#pragma unroll
      for (int jj = 0; jj < 4; ++jj) {
        const int grow = brow + wm * 128 + mi * 16 + l4 * 4 + jj;
        float nsum = 0.0f;
#pragma unroll
        for (int ni = 0; ni < 4; ++ni) {
          const int gcol = bcol + wn * 64 + ni * 16 + l15;
          float y = fmaxf(acc[mi][ni][jj] + bias[gcol], 0.0f);
          y = gamma[gcol] * (y - mean[gcol]) / sqrtf(var[gcol] + BN_EPS) +
              beta[gcol];
          Ch[(size_t)grow * N + gcol] = (f16)y;
          nsum += y * y;
        }
        nsum += __shfl_xor(nsum, 1);
        nsum += __shfl_xor(nsum, 2);
        nsum += __shfl_xor(nsum, 4);
        nsum += __shfl_xor(nsum, 8);
        if (l15 == 0) atomicAdd(&norm2[grow], nsum);
      }
    }
  }
}

// ---------------------------------------------------------------- 128^2 GEMM
// BK=64, slot-XOR both-sides swizzle (R15-verified).
template <int BM, int BN, int EPI>
__global__ __launch_bounds__(256, 2) void gemm_kernel(
    const f16* __restrict__ Ah, const f16* __restrict__ Bh, int M, int N,
    int K, long long sAb, long long sBb, long long sCb,
    float* __restrict__ Cf, f16* __restrict__ Ch,
    const float* __restrict__ bias, const float* __restrict__ gamma,
    const float* __restrict__ beta, const float* __restrict__ mean,
    const float* __restrict__ var, float* __restrict__ norm2) {
  (void)M;
  constexpr int BK = 64;
  constexpr int WM = BM / 2, WN = BN / 2;
  constexpr int FM = WM / 16, FN = WN / 16;

  __shared__ __align__(16) f16 lds[(BM + BN) * BK];
  f16* sA = lds;
  f16* sB = lds + BM * BK;

  const int b = blockIdx.z;
  const f16* pA = Ah + (size_t)b * sAb;
  const f16* pB = Bh + (size_t)b * sBb;

  const int brow = blockIdx.y * BM, bcol = blockIdx.x * BN;
  const int t = threadIdx.x, wave = t >> 6, lane = t & 63;
  const int wr = wave >> 1, wc = wave & 1;

  f32x4 acc[FM][FN] = {};

  constexpr int A_CH = BM / 8, B_CH = BN / 8;
  constexpr int TOT = A_CH + B_CH;

  const int srow8 = lane >> 3;
  const int scol = ((lane & 7) ^ ((lane >> 3) & 7)) * 8;
  const int lr = lane & 15;
  const int l4 = lane >> 4;

  for (int k0 = 0; k0 < K; k0 += BK) {
    for (int id = wave; id < TOT; id += 4) {
      const f16* g;
      f16* l;
      if (id < A_CH) {
        g = pA + (size_t)(brow + id * 8 + srow8) * K + k0 + scol;
        l = sA + id * 8 * BK + lane * 8;
      } else {
        int c = id - A_CH;
        g = pB + (size_t)(bcol + c * 8 + srow8) * K + k0 + scol;
        l = sB + c * 8 * BK + lane * 8;
      }
      gload_lds16(g, l);
    }
    asm volatile("s_waitcnt vmcnt(0)" ::: "memory");
    __syncthreads();

#pragma unroll
    for (int kk = 0; kk < 2; ++kk) {
      const int s0 = l4 + kk * 4;
      f16x8 fa[FM], fb[FN];
#pragma unroll
      for (int mi = 0; mi < FM; ++mi) {
        const int r = wr * WM + mi * 16 + lr;
        fa[mi] = *(const f16x8*)(sA + r * BK + (s0 ^ (r & 7)) * 8);
      }
#pragma unroll
      for (int ni = 0; ni < FN; ++ni) {
        const int r = wc * WN + ni * 16 + lr;
        fb[ni] = *(const f16x8*)(sB + r * BK + (s0 ^ (r & 7)) * 8);
      }
#pragma unroll
      for (int mi = 0; mi < FM; ++mi)
#pragma unroll
        for (int ni = 0; ni < FN; ++ni)
          acc[mi][ni] = __builtin_amdgcn_mfma_f32_16x16x32_f16(
              fa[mi], fb[ni], acc[mi][ni], 0, 0, 0);
    }
    __syncthreads();
  }

#pragma unroll
  for (int mi = 0; mi < FM; ++mi) {
#pragma unroll
    for (int j = 0; j < 4; ++j) {
      const int grow = brow + wr * WM + mi * 16 + (lane >> 4) * 4 + j;
      float nsum = 0.0f;
#pragma unroll
      for (int ni = 0; ni < FN; ++ni) {
        const int gcol = bcol + wc * WN + ni * 16 + lr;
        float val = acc[mi][ni][j];
        if constexpr (EPI == EPI_RAW) {
          Cf[(size_t)b * sCb + (size_t)grow * N + gcol] = val;
        } else if constexpr (EPI == EPI_HALF) {
          Ch[(size_t)b * sCb + (size_t)grow * N + gcol] = (f16)val;
        } else {
          float y = fmaxf(val + bias[gcol], 0.0f);
          y = gamma[gcol] * (y - mean[gcol]) / sqrtf(var[gcol] + BN_EPS) +
              beta[gcol];
          if constexpr (EPI == EPI_BN_F32) {
            Cf[(size_t)grow * N + gcol] = y;
          } else {  // EPI_HALF_NORM
            Ch[(size_t)grow * N + gcol] = (f16)y;
            nsum += y * y;
          }
        }
      }
      if constexpr (EPI == EPI_HALF_NORM) {
        nsum += __shfl_xor(nsum, 1);
        nsum += __shfl_xor(nsum, 2);
        nsum += __shfl_xor(nsum, 4);
        nsum += __shfl_xor(nsum, 8);
        if (lr == 0) atomicAdd(&norm2[grow], nsum);
      }
    }
  }
}

// ---------------------------------------------------------------- helpers
__global__ __launch_bounds__(256) void cvt_multi_kernel(
    const float* __restrict__ s0, f16* __restrict__ d0,
    const float* __restrict__ s1, f16* __restrict__ d1,
    const float* __restrict__ s2, f16* __restrict__ d2,
    const float* __restrict__ s3, f16* __restrict__ d3,
    const float* __restrict__ s4, f16* __restrict__ d4, int c0, int c1,
    int c2, int c3, int c4) {
  int i = blockIdx.x * 256 + threadIdx.x;
  if (i >= c4) return;
  const float* s;
  f16* d;
  int j;
  if (i < c0) {
    s = s0; d = d0; j = i;
  } else if (i < c1) {
    s = s1; d = d1; j = i - c0;
  } else if (i < c2) {
    s = s2; d = d2; j = i - c1;
  } else if (i < c3) {
    s = s3; d = d3; j = i - c2;
  } else {
    s = s4; d = d4; j = i - c3;
  }
  fv4 v = ((const fv4*)s)[j];
  f16x4 h;
#pragma unroll
  for (int k = 0; k < 4; ++k) h[k] = (f16)v[k];
  ((f16x4*)d)[j] = h;
}

// mean over trailing 7x7=49; one block per (b,n). R16: coalesced via LDS
// round-trip -- 4 chunks of 256 d; (a) 256 threads vec4-load the chunk's
// 256*49 floats coalesced into LDS; (b) thread t sums lds[t*49..+48] in
// the SAME sequential order as the old scalar version (bit-identical out).
__global__ __launch_bounds__(256) void pool_kernel(const float* __restrict__ x,
                                                   f16* __restrict__ ah) {
  __shared__ float buf[12544];  // 256*49 floats = 49 KiB
  const int bn = blockIdx.x;
  const int t = threadIdx.x;
  const float* base = x + (size_t)bn * 50176;  // 1024*49
#pragma unroll
  for (int c = 0; c < 4; ++c) {
    const fv4* src = (const fv4*)(base + c * 12544);
    for (int i = t; i < 3136; i += 256) ((fv4*)buf)[i] = src[i];
    __syncthreads();
    const float* p = buf + t * 49;
    float s = 0.f;
#pragma unroll
    for (int j = 0; j < 49; ++j) s += p[j];
    ah[(size_t)bn * 1024 + c * 256 + t] = (f16)(s / 49.0f);
    __syncthreads();
  }
}

__global__ __launch_bounds__(256) void softmax_kernel(
    const float* __restrict__ raw, const float* __restrict__ qn2,
    const float* __restrict__ kn2, const float* __restrict__ vn2,
    const int* __restrict__ nvalid, f16* __restrict__ wgt) {
  const int n = blockIdx.x;
  const int b = blockIdx.y;
  const int row = b * 64 + n;
  const float* r = raw + (size_t)row * 2048;
  const int nv = nvalid[b];
  const float qs = 100.0f / fmaxf(sqrtf(qn2[row]), 1e-12f);

  __shared__ float sl[2048];
  __shared__ float red[4];
  const int t = threadIdx.x;

  float mx = -3.0e38f;
  for (int m = t; m < 2048; m += 256) {
    float v = -3.0e38f;
    if (m < nv) {
      float ks = 1.0f / fmaxf(sqrtf(kn2[b * 2048 + m]), 1e-12f);
      v = r[m] * qs * ks;
    }
    sl[m] = v;
    mx = fmaxf(mx, v);
  }
#pragma unroll
  for (int s = 32; s; s >>= 1) mx = fmaxf(mx, __shfl_xor(mx, s));
  if ((t & 63) == 0) red[t >> 6] = mx;
  __syncthreads();
  mx = fmaxf(fmaxf(red[0], red[1]), fmaxf(red[2], red[3]));
  __syncthreads();

  float sum = 0.f;
  for (int m = t; m < 2048; m += 256) {
    float e = (m < nv) ? __expf(sl[m] - mx) : 0.0f;
    sl[m] = e;
    sum += e;
  }
#pragma unroll
  for (int s = 32; s; s >>= 1) sum += __shfl_xor(sum, s);
  if ((t & 63) == 0) red[t >> 6] = sum;
  __syncthreads();
  sum = red[0] + red[1] + red[2] + red[3];
  const float inv = 1.0f / sum;

  for (int m = t; m < 2048; m += 256) {
    float vs = 1.0f / fmaxf(sqrtf(vn2[b * 2048 + m]), 1e-12f);
    wgt[(size_t)row * 2048 + m] = (f16)(sl[m] * inv * vs);
  }
}

__global__ __launch_bounds__(256) void add_kernel(const float* __restrict__ x,
                                                  const float* __restrict__ fc,
                                                  float* __restrict__ out,
                                                  int n4) {
  int i = blockIdx.x * 256 + threadIdx.x;
  if (i >= n4) return;
  fv4 v = ((const fv4*)x)[i];
  int e = i * 4;
#pragma unroll
  for (int j = 0; j < 4; ++j) v[j] += fc[(e + j) / 49];
  ((fv4*)out)[i] = v;
}

// ---------------------------------------------------------------- launch
extern "C" void kernel_launch(void* const* d_in, const int* in_sizes, int n_in,
                              void* d_out, int out_size, void* d_ws,
                              size_t ws_size, hipStream_t stream) {
  (void)in_sizes; (void)n_in; (void)out_size; (void)ws_size;
  const float* x = (const float*)d_in[0];
  const float* xc = (const float*)d_in[1];
  const int* nvp = (const int*)d_in[2];
  const float* qW = (const float*)d_in[3];
  const float* qB = (const float*)d_in[4];
  const float* qG = (const float*)d_in[5];
  const float* qBe = (const float*)d_in[6];
  const float* qM = (const float*)d_in[7];
  const float* qV = (const float*)d_in[8];
  const float* kW = (const float*)d_in[9];
  const float* kB = (const float*)d_in[10];
  const float* kG = (const float*)d_in[11];
  const float* kBe = (const float*)d_in[12];
  const float* kM = (const float*)d_in[13];
  const float* kV = (const float*)d_in[14];
  const float* vW = (const float*)d_in[15];
  const float* vB = (const float*)d_in[16];
  const float* vG = (const float*)d_in[17];
  const float* vBe = (const float*)d_in[18];
  const float* vM = (const float*)d_in[19];
  const float* vV = (const float*)d_in[20];
  const float* fW = (const float*)d_in[21];
  const float* fB = (const float*)d_in[22];
  const float* fG = (const float*)d_in[23];
  const float* fBe = (const float*)d_in[24];
  const float* fM = (const float*)d_in[25];
  const float* fV = (const float*)d_in[26];
  float* out = (float*)d_out;

  const int NRq = 512;
  const int NRc = 16384;
  const int Dd = 1024, Cc = 2048, D1 = 2048, D2 = 2048, Mm = 2048;

  char* p = (char*)d_ws;
  auto take = [&](size_t bytes) -> char* {
    char* r = p;
    p += (bytes + 255) & ~(size_t)255;
    return r;
  };
  f16* xch = (f16*)take((size_t)NRc * Cc * 2);
  f16* kh = (f16*)take((size_t)NRc * D1 * 2);
  f16* vT = (f16*)take((size_t)NRc * D2 * 2);  // [b][d][m] transposed values
  f16* qWh = (f16*)take((size_t)D1 * Dd * 2);
  f16* kWh = (f16*)take((size_t)D1 * Cc * 2);
  f16* vWh = (f16*)take((size_t)D2 * Cc * 2);
  f16* fWh = (f16*)take((size_t)Dd * D2 * 2);
  f16* Aph = (f16*)take((size_t)NRq * Dd * 2);
  f16* qh = (f16*)take((size_t)NRq * D1 * 2);
  float* norms = (float*)take((size_t)(NRq + 2 * NRc) * 4);
  float* qn2 = norms;
  float* kn2 = norms + NRq;
  float* vn2 = norms + NRq + NRc;
  float* raw = (float*)take((size_t)NRq * Mm * 4);
  f16* wgt = (f16*)take((size_t)NRq * Mm * 2);
  f16* wvh = (f16*)take((size_t)NRq * D2 * 2);
  float* fctx = (float*)take((size_t)NRq * Dd * 4);

  // all fp32->fp16 conversions in one kernel
  const int n4_0 = NRc * Cc / 4;           // xc
  const int n4_1 = D1 * Dd / 4;            // qW
  const int n4_2 = D1 * Cc / 4;            // kW
  const int n4_3 = D2 * Cc / 4;            // vW
  const int n4_4 = Dd * D2 / 4;            // fW
  const int cum0 = n4_0, cum1 = cum0 + n4_1, cum2 = cum1 + n4_2,
            cum3 = cum2 + n4_3, cum4 = cum3 + n4_4;
  cvt_multi_kernel<<<dim3((cum4 + 255) / 256), 256, 0, stream>>>(
      xc, xch, qW, qWh, kW, kWh, vW, vWh, fW, fWh, cum0, cum1, cum2, cum3,
      cum4);
  pool_kernel<<<dim3(512), 256, 0, stream>>>(x, Aph);
  hipMemsetAsync(norms, 0, (size_t)(NRq + 2 * NRc) * 4, stream);

  // Q: 128^2 kernel (BM=32: 256 blocks), single-pass fp16
  gemm_kernel<32, 128, EPI_HALF_NORM>
      <<<dim3(D1 / 128, NRq / 32, 1), 256, 0, stream>>>(
          Aph, qWh, NRq, D1, Dd, 0, 0, 0, nullptr, qh, qB, qG, qBe, qM, qV,
          qn2);
  // K: 8-phase 256^2, single-pass fp16
  gemm8_kernel<EPI_HALF_NORM>
      <<<dim3((NRc / 256) * (D1 / 256)), 512, 0, stream>>>(
          xch, kWh, D1, Cc, D1 / 256, kh, kB, kG, kBe, kM, kV, kn2);
  // V^T: 8-phase 256^2, A=vW rows=d2, B=xc rows=items -> C[d][b*m]
  gemm8_kernel<EPI_HALF_NORM_T>
      <<<dim3((D2 / 256) * (NRc / 256)), 512, 0, stream>>>(
          vWh, xch, NRc, Cc, NRc / 256, vT, vB, vG, vBe, vM, vV, vn2);
  // sim (batched): single-pass fp16 -> raw fp32 (BM=32: 256 blocks)
  gemm_kernel<32, 128, EPI_RAW><<<dim3(Mm / 128, 2, 8), 256, 0, stream>>>(
      qh, kh, 64, Mm, D1, (long long)64 * D1, (long long)Mm * D1,
      (long long)64 * Mm, raw, nullptr, nullptr, nullptr, nullptr, nullptr,
      nullptr, nullptr);
  softmax_kernel<<<dim3(64, 8), 256, 0, stream>>>(raw, qn2, kn2, vn2, nvp, wgt);
  gemm_kernel<32, 128, EPI_HALF><<<dim3(D2 / 128, 2, 8), 256, 0, stream>>>(
      wgt, vT, 64, D2, Mm, (long long)64 * Mm, (long long)D2 * Mm,
      (long long)64 * D2, nullptr, wvh, nullptr, nullptr, nullptr, nullptr,
      nullptr, nullptr);
  // f: BM=32 -> 128 blocks
  gemm_kernel<32, 128, EPI_BN_F32>
      <<<dim3(Dd / 128, NRq / 32, 1), 256, 0, stream>>>(
          wvh, fWh, NRq, Dd, D2, 0, 0, 0, fctx, nullptr, fB, fG, fBe, fM, fV,
          nullptr);
  add_kernel<<<dim3(25690112 / 4 / 256), 256, 0, stream>>>(x, fctx, out,
                                                           25690112 / 4);
}

// Round 17
// 551.508 us; speedup vs baseline: 1.0175x; 1.0175x over previous
//
#include <hip/hip_runtime.h>

typedef _Float16 f16;
typedef _Float16 f16x8 __attribute__((ext_vector_type(8)));
typedef _Float16 f16x4 __attribute__((ext_vector_type(4)));
typedef float f32x4 __attribute__((ext_vector_type(4)));
typedef float fv4 __attribute__((ext_vector_type(4)));

#define BN_EPS 1e-5f

constexpr int EPI_RAW = 0;         // write fp32 C (no transform)       [sim]
constexpr int EPI_HALF_NORM = 2;   // BN+ReLU -> fp16 + ROW norm2       [Q,K]
constexpr int EPI_HALF = 3;        // fp16 C (no transform)             [wv]
constexpr int EPI_BN_F32 = 4;      // BN+ReLU -> fp32 C                 [f]
constexpr int EPI_HALF_NORM_T = 5; // BN(row)+ReLU -> fp16 + COL norm2  [V^T]

__device__ __forceinline__ void gload_lds16(const void* g, void* l) {
  __builtin_amdgcn_global_load_lds(
      (const __attribute__((address_space(1))) unsigned int*)g,
      (__attribute__((address_space(3))) unsigned int*)l, 16, 0, 0);
}

// ================================================================= gemm8
// R12-verified kernel (K/V ~157 us @ 40% MfmaUtil). 256x256 tile, BK=64,
// 8 waves (2Mx4N), 8-phase / 1-barrier-per-phase / counted-vmcnt,
// cross-phase register prefetch with named frags. FROZEN.
#define LDSA(d0, d1, d2, d3, par, kk, mi0)            \
  {                                                   \
    const int ab_ = (par)*65536 + (kk)*16384 + aoff;  \
    d0 = ldf(ab_ + (((mi0) + 0) << 10));              \
    d1 = ldf(ab_ + (((mi0) + 1) << 10));              \
    d2 = ldf(ab_ + (((mi0) + 2) << 10));              \
    d3 = ldf(ab_ + (((mi0) + 3) << 10));              \
  }
#define LDSB(d0, d1, d2, d3, par, kk)                 \
  {                                                   \
    const int bb_ = (par)*65536 + (kk)*16384 + boff;  \
    d0 = ldf(bb_ + (0 << 10));                        \
    d1 = ldf(bb_ + (1 << 10));                        \
    d2 = ldf(bb_ + (2 << 10));                        \
    d3 = ldf(bb_ + (3 << 10));                        \
  }
#define MM16(a0, a1, a2, a3, b0, b1, b2, b3, mi0)                              \
  __builtin_amdgcn_s_setprio(1);                                               \
  acc[(mi0) + 0][0] = __builtin_amdgcn_mfma_f32_16x16x32_f16(a0, b0, acc[(mi0) + 0][0], 0, 0, 0); \
  acc[(mi0) + 0][1] = __builtin_amdgcn_mfma_f32_16x16x32_f16(a0, b1, acc[(mi0) + 0][1], 0, 0, 0); \
  acc[(mi0) + 0][2] = __builtin_amdgcn_mfma_f32_16x16x32_f16(a0, b2, acc[(mi0) + 0][2], 0, 0, 0); \
  acc[(mi0) + 0][3] = __builtin_amdgcn_mfma_f32_16x16x32_f16(a0, b3, acc[(mi0) + 0][3], 0, 0, 0); \
  acc[(mi0) + 1][0] = __builtin_amdgcn_mfma_f32_16x16x32_f16(a1, b0, acc[(mi0) + 1][0], 0, 0, 0); \
  acc[(mi0) + 1][1] = __builtin_amdgcn_mfma_f32_16x16x32_f16(a1, b1, acc[(mi0) + 1][1], 0, 0, 0); \
  acc[(mi0) + 1][2] = __builtin_amdgcn_mfma_f32_16x16x32_f16(a1, b2, acc[(mi0) + 1][2], 0, 0, 0); \
  acc[(mi0) + 1][3] = __builtin_amdgcn_mfma_f32_16x16x32_f16(a1, b3, acc[(mi0) + 1][3], 0, 0, 0); \
  acc[(mi0) + 2][0] = __builtin_amdgcn_mfma_f32_16x16x32_f16(a2, b0, acc[(mi0) + 2][0], 0, 0, 0); \
  acc[(mi0) + 2][1] = __builtin_amdgcn_mfma_f32_16x16x32_f16(a2, b1, acc[(mi0) + 2][1], 0, 0, 0); \
  acc[(mi0) + 2][2] = __builtin_amdgcn_mfma_f32_16x16x32_f16(a2, b2, acc[(mi0) + 2][2], 0, 0, 0); \
  acc[(mi0) + 2][3] = __builtin_amdgcn_mfma_f32_16x16x32_f16(a2, b3, acc[(mi0) + 2][3], 0, 0, 0); \
  acc[(mi0) + 3][0] = __builtin_amdgcn_mfma_f32_16x16x32_f16(a3, b0, acc[(mi0) + 3][0], 0, 0, 0); \
  acc[(mi0) + 3][1] = __builtin_amdgcn_mfma_f32_16x16x32_f16(a3, b1, acc[(mi0) + 3][1], 0, 0, 0); \
  acc[(mi0) + 3][2] = __builtin_amdgcn_mfma_f32_16x16x32_f16(a3, b2, acc[(mi0) + 3][2], 0, 0, 0); \
  acc[(mi0) + 3][3] = __builtin_amdgcn_mfma_f32_16x16x32_f16(a3, b3, acc[(mi0) + 3][3], 0, 0, 0); \
  __builtin_amdgcn_s_setprio(0);

template <int EPI>
__global__ __launch_bounds__(512, 1) void gemm8_kernel(
    const f16* __restrict__ A, const f16* __restrict__ Bh, int N, int K,
    int gx, f16* __restrict__ Ch, const float* __restrict__ bias,
    const float* __restrict__ gamma, const float* __restrict__ beta,
    const float* __restrict__ mean, const float* __restrict__ var,
    float* __restrict__ norm2) {
  __shared__ __align__(16) char smem[131072];

  const int nwg = gridDim.x;
  const int bid = blockIdx.x;
  const int swz = (bid & 7) * (nwg >> 3) + (bid >> 3);  // XCD swizzle (nwg%8==0)
  const int brow = (swz / gx) * 256;
  const int bcol = (swz % gx) * 256;

  const int tid = threadIdx.x;
  const int lane = tid & 63;
  const int w = tid >> 6;
  const int wm = w >> 2;     // 0..1
  const int wn = w & 3;      // 0..3
  const int l15 = lane & 15;
  const int l4 = lane >> 4;  // kslot 0..3

  const int NT = K >> 6;

  // staging: source chunk permutation (slot-xor within row), coalesced rows
  const int c0 = tid ^ ((tid >> 3) & 3);
  const int srow = c0 >> 2;     // 0..127 (second chunk: +128)
  const int sk = (c0 & 3) * 8;  // element offset within 32-k row
  const size_t gA0 = (size_t)(brow + srow) * K + sk;
  const size_t gB0 = (size_t)(bcol + srow) * K + sk;
  const size_t gstep = (size_t)128 * K;
  char* const ldst = smem + tid * 16;

  auto STAGE = [&](int v, int par, int op, int kk) {
    if (v >= NT) return;
    const int k0 = v * 64 + kk * 32;
    const f16* g = (op == 0) ? (A + gA0 + k0) : (Bh + gB0 + k0);
    char* l = ldst + par * 65536 + op * 32768 + kk * 16384;
    gload_lds16(g, l);
    gload_lds16(g + gstep, l + 8192);
  };

  f32x4 acc[8][4] = {};

  // fragment read swizzle + per-thread bases (byte offsets within piece)
  const int kx16 = (l4 ^ ((l15 >> 1) & 3)) * 16;
  const int aoff = ((wm * 128 + l15) << 6) + kx16;
  const int boff = 32768 + ((wn * 64 + l15) << 6) + kx16;

  auto ldf = [&](int off) -> f16x8 { return *(const f16x8*)(smem + off); };
  auto BAR = [&]() { __builtin_amdgcn_s_barrier(); };
  auto VMID = [&](int tcur) {
    if (tcur + 2 >= NT)
      asm volatile("s_waitcnt vmcnt(0)" ::: "memory");
    else
      asm volatile("s_waitcnt vmcnt(4)" ::: "memory");
  };
  auto VEND = [&](int tcur) {
    if (tcur + 2 < NT) asm volatile("s_waitcnt vmcnt(4)" ::: "memory");
  };

  f16x8 aX0, aX1, aX2, aX3, aY0, aY1, aY2, aY3;
  f16x8 bX0, bX1, bX2, bX3, bY0, bY1, bY2, bY3;

  // prologue: tile0 fully + tile1.k0 halves (6 events, 12 loads)
  STAGE(0, 0, 0, 0);
  STAGE(0, 0, 1, 0);
  STAGE(0, 0, 0, 1);
  STAGE(0, 0, 1, 1);
  STAGE(1, 1, 0, 0);
  STAGE(1, 1, 1, 0);
  asm volatile("s_waitcnt vmcnt(4)" ::: "memory");
  __builtin_amdgcn_s_barrier();

  // initial fragments for P1 (buf0.k0)
  LDSA(aX0, aX1, aX2, aX3, 0, 0, 0);
  LDSB(bX0, bX1, bX2, bX3, 0, 0);

  for (int t = 0; t < NT; t += 2) {
    STAGE(t + 1, 1, 0, 1);
    MM16(aX0, aX1, aX2, aX3, bX0, bX1, bX2, bX3, 0);
    LDSA(aY0, aY1, aY2, aY3, 0, 0, 4);
    BAR();
    STAGE(t + 1, 1, 1, 1);
    MM16(aY0, aY1, aY2, aY3, bX0, bX1, bX2, bX3, 4);
    LDSA(aX0, aX1, aX2, aX3, 0, 1, 0);
    LDSB(bY0, bY1, bY2, bY3, 0, 1);
    BAR();
    STAGE(t + 2, 0, 0, 0);
    MM16(aX0, aX1, aX2, aX3, bY0, bY1, bY2, bY3, 0);
    LDSA(aY0, aY1, aY2, aY3, 0, 1, 4);
    BAR();
    STAGE(t + 2, 0, 1, 0);
    VMID(t);
    MM16(aY0, aY1, aY2, aY3, bY0, bY1, bY2, bY3, 4);
    LDSA(aX0, aX1, aX2, aX3, 1, 0, 0);
    LDSB(bX0, bX1, bX2, bX3, 1, 0);
    BAR();
    STAGE(t + 2, 0, 0, 1);
    MM16(aX0, aX1, aX2, aX3, bX0, bX1, bX2, bX3, 0);
    LDSA(aY0, aY1, aY2, aY3, 1, 0, 4);
    BAR();
    STAGE(t + 2, 0, 1, 1);
    MM16(aY0, aY1, aY2, aY3, bX0, bX1, bX2, bX3, 4);
    LDSA(aX0, aX1, aX2, aX3, 1, 1, 0);
    LDSB(bY0, bY1, bY2, bY3, 1, 1);
    BAR();
    STAGE(t + 3, 1, 0, 0);
    MM16(aX0, aX1, aX2, aX3, bY0, bY1, bY2, bY3, 0);
    LDSA(aY0, aY1, aY2, aY3, 1, 1, 4);
    BAR();
    STAGE(t + 3, 1, 1, 0);
    VEND(t);
    MM16(aY0, aY1, aY2, aY3, bY0, bY1, bY2, bY3, 4);
    LDSA(aX0, aX1, aX2, aX3, 0, 0, 0);
    LDSB(bX0, bX1, bX2, bX3, 0, 0);
    BAR();
  }

  // epilogue: C/D layout col=lane&15, row=(lane>>4)*4+j
  if constexpr (EPI == EPI_HALF_NORM_T) {
    float colsum[4] = {0.f, 0.f, 0.f, 0.f};
#pragma unroll
    for (int mi = 0; mi < 8; ++mi) {
#pragma unroll
      for (int jj = 0; jj < 4; ++jj) {
        const int grow = brow + wm * 128 + mi * 16 + l4 * 4 + jj;  // d index
        const float bb = bias[grow], gg = gamma[grow], mm = mean[grow];
        const float vv = var[grow], be = beta[grow];
#pragma unroll
        for (int ni = 0; ni < 4; ++ni) {
          const int gcol = bcol + wn * 64 + ni * 16 + l15;
          float y = fmaxf(acc[mi][ni][jj] + bb, 0.0f);
          y = gg * (y - mm) / sqrtf(vv + BN_EPS) + be;
          Ch[(size_t)grow * N + gcol] = (f16)y;
          colsum[ni] += y * y;
        }
      }
    }
#pragma unroll
    for (int ni = 0; ni < 4; ++ni) {
      float s = colsum[ni];
      s += __shfl_xor(s, 16);
      s += __shfl_xor(s, 32);
      if (l4 == 0)
        atomicAdd(&norm2[bcol + wn * 64 + ni * 16 + l15], s);
    }
  } else {
#pragma unroll
    for (int mi = 0; mi < 8; ++mi) {
#pragma unroll
      for (int jj = 0; jj < 4; ++jj) {
        const int grow = brow + wm * 128 + mi * 16 + l4 * 4 + jj;
        float nsum = 0.0f;
#pragma unroll
        for (int ni = 0; ni < 4; ++ni) {
          const int gcol = bcol + wn * 64 + ni * 16 + l15;
          float y = fmaxf(acc[mi][ni][jj] + bias[gcol], 0.0f);
          y = gamma[gcol] * (y - mean[gcol]) / sqrtf(var[gcol] + BN_EPS) +
              beta[gcol];
          Ch[(size_t)grow * N + gcol] = (f16)y;
          nsum += y * y;
        }
        nsum += __shfl_xor(nsum, 1);
        nsum += __shfl_xor(nsum, 2);
        nsum += __shfl_xor(nsum, 4);
        nsum += __shfl_xor(nsum, 8);
        if (l15 == 0) atomicAdd(&norm2[grow], nsum);
      }
    }
  }
}

// ---------------------------------------------------------------- 128^2 GEMM
// BK=64, slot-XOR both-sides swizzle (R15-verified).
template <int BM, int BN, int EPI>
__global__ __launch_bounds__(256, 2) void gemm_kernel(
    const f16* __restrict__ Ah, const f16* __restrict__ Bh, int M, int N,
    int K, long long sAb, long long sBb, long long sCb,
    float* __restrict__ Cf, f16* __restrict__ Ch,
    const float* __restrict__ bias, const float* __restrict__ gamma,
    const float* __restrict__ beta, const float* __restrict__ mean,
    const float* __restrict__ var, float* __restrict__ norm2) {
  (void)M;
  constexpr int BK = 64;
  constexpr int WM = BM / 2, WN = BN / 2;
  constexpr int FM = WM / 16, FN = WN / 16;

  __shared__ __align__(16) f16 lds[(BM + BN) * BK];
  f16* sA = lds;
  f16* sB = lds + BM * BK;

  const int b = blockIdx.z;
  const f16* pA = Ah + (size_t)b * sAb;
  const f16* pB = Bh + (size_t)b * sBb;

  const int brow = blockIdx.y * BM, bcol = blockIdx.x * BN;
  const int t = threadIdx.x, wave = t >> 6, lane = t & 63;
  const int wr = wave >> 1, wc = wave & 1;

  f32x4 acc[FM][FN] = {};

  constexpr int A_CH = BM / 8, B_CH = BN / 8;
  constexpr int TOT = A_CH + B_CH;

  const int srow8 = lane >> 3;
  const int scol = ((lane & 7) ^ ((lane >> 3) & 7)) * 8;
  const int lr = lane & 15;
  const int l4 = lane >> 4;

  for (int k0 = 0; k0 < K; k0 += BK) {
    for (int id = wave; id < TOT; id += 4) {
      const f16* g;
      f16* l;
      if (id < A_CH) {
        g = pA + (size_t)(brow + id * 8 + srow8) * K + k0 + scol;
        l = sA + id * 8 * BK + lane * 8;
      } else {
        int c = id - A_CH;
        g = pB + (size_t)(bcol + c * 8 + srow8) * K + k0 + scol;
        l = sB + c * 8 * BK + lane * 8;
      }
      gload_lds16(g, l);
    }
    asm volatile("s_waitcnt vmcnt(0)" ::: "memory");
    __syncthreads();

#pragma unroll
    for (int kk = 0; kk < 2; ++kk) {
      const int s0 = l4 + kk * 4;
      f16x8 fa[FM], fb[FN];
#pragma unroll
      for (int mi = 0; mi < FM; ++mi) {
        const int r = wr * WM + mi * 16 + lr;
        fa[mi] = *(const f16x8*)(sA + r * BK + (s0 ^ (r & 7)) * 8);
      }
#pragma unroll
      for (int ni = 0; ni < FN; ++ni) {
        const int r = wc * WN + ni * 16 + lr;
        fb[ni] = *(const f16x8*)(sB + r * BK + (s0 ^ (r & 7)) * 8);
      }
#pragma unroll
      for (int mi = 0; mi < FM; ++mi)
#pragma unroll
        for (int ni = 0; ni < FN; ++ni)
          acc[mi][ni] = __builtin_amdgcn_mfma_f32_16x16x32_f16(
              fa[mi], fb[ni], acc[mi][ni], 0, 0, 0);
    }
    __syncthreads();
  }

#pragma unroll
  for (int mi = 0; mi < FM; ++mi) {
#pragma unroll
    for (int j = 0; j < 4; ++j) {
      const int grow = brow + wr * WM + mi * 16 + (lane >> 4) * 4 + j;
      float nsum = 0.0f;
#pragma unroll
      for (int ni = 0; ni < FN; ++ni) {
        const int gcol = bcol + wc * WN + ni * 16 + lr;
        float val = acc[mi][ni][j];
        if constexpr (EPI == EPI_RAW) {
          Cf[(size_t)b * sCb + (size_t)grow * N + gcol] = val;
        } else if constexpr (EPI == EPI_HALF) {
          Ch[(size_t)b * sCb + (size_t)grow * N + gcol] = (f16)val;
        } else {
          float y = fmaxf(val + bias[gcol], 0.0f);
          y = gamma[gcol] * (y - mean[gcol]) / sqrtf(var[gcol] + BN_EPS) +
              beta[gcol];
          if constexpr (EPI == EPI_BN_F32) {
            Cf[(size_t)grow * N + gcol] = y;
          } else {  // EPI_HALF_NORM
            Ch[(size_t)grow * N + gcol] = (f16)y;
            nsum += y * y;
          }
        }
      }
      if constexpr (EPI == EPI_HALF_NORM) {
        nsum += __shfl_xor(nsum, 1);
        nsum += __shfl_xor(nsum, 2);
        nsum += __shfl_xor(nsum, 4);
        nsum += __shfl_xor(nsum, 8);
        if (lr == 0) atomicAdd(&norm2[grow], nsum);
      }
    }
  }
}

// ---------------------------------------------------------------- helpers
__global__ __launch_bounds__(256) void cvt_multi_kernel(
    const float* __restrict__ s0, f16* __restrict__ d0,
    const float* __restrict__ s1, f16* __restrict__ d1,
    const float* __restrict__ s2, f16* __restrict__ d2,
    const float* __restrict__ s3, f16* __restrict__ d3,
    const float* __restrict__ s4, f16* __restrict__ d4, int c0, int c1,
    int c2, int c3, int c4) {
  int i = blockIdx.x * 256 + threadIdx.x;
  if (i >= c4) return;
  const float* s;
  f16* d;
  int j;
  if (i < c0) {
    s = s0; d = d0; j = i;
  } else if (i < c1) {
    s = s1; d = d1; j = i - c0;
  } else if (i < c2) {
    s = s2; d = d2; j = i - c1;
  } else if (i < c3) {
    s = s3; d = d3; j = i - c2;
  } else {
    s = s4; d = d4; j = i - c3;
  }
  fv4 v = ((const fv4*)s)[j];
  f16x4 h;
#pragma unroll
  for (int k = 0; k < 4; ++k) h[k] = (f16)v[k];
  ((f16x4*)d)[j] = h;
}

__global__ __launch_bounds__(256) void pool_kernel(const float* __restrict__ x,
                                                   f16* __restrict__ ah) {
  int bn = blockIdx.x;
  const float* base = x + (size_t)bn * 1024 * 49;
  for (int d = threadIdx.x; d < 1024; d += 256) {
    const float* p = base + (size_t)d * 49;
    float s = 0.f;
#pragma unroll
    for (int j = 0; j < 49; ++j) s += p[j];
    ah[(size_t)bn * 1024 + d] = (f16)(s / 49.0f);
  }
}

__global__ __launch_bounds__(256) void softmax_kernel(
    const float* __restrict__ raw, const float* __restrict__ qn2,
    const float* __restrict__ kn2, const float* __restrict__ vn2,
    const int* __restrict__ nvalid, f16* __restrict__ wgt) {
  const int n = blockIdx.x;
  const int b = blockIdx.y;
  const int row = b * 64 + n;
  const float* r = raw + (size_t)row * 2048;
  const int nv = nvalid[b];
  const float qs = 100.0f / fmaxf(sqrtf(qn2[row]), 1e-12f);

  __shared__ float sl[2048];
  __shared__ float red[4];
  const int t = threadIdx.x;

  float mx = -3.0e38f;
  for (int m = t; m < 2048; m += 256) {
    float v = -3.0e38f;
    if (m < nv) {
      float ks = 1.0f / fmaxf(sqrtf(kn2[b * 2048 + m]), 1e-12f);
      v = r[m] * qs * ks;
    }
    sl[m] = v;
    mx = fmaxf(mx, v);
  }
#pragma unroll
  for (int s = 32; s; s >>= 1) mx = fmaxf(mx, __shfl_xor(mx, s));
  if ((t & 63) == 0) red[t >> 6] = mx;
  __syncthreads();
  mx = fmaxf(fmaxf(red[0], red[1]), fmaxf(red[2], red[3]));
  __syncthreads();

  float sum = 0.f;
  for (int m = t; m < 2048; m += 256) {
    float e = (m < nv) ? __expf(sl[m] - mx) : 0.0f;
    sl[m] = e;
    sum += e;
  }
#pragma unroll
  for (int s = 32; s; s >>= 1) sum += __shfl_xor(sum, s);
  if ((t & 63) == 0) red[t >> 6] = sum;
  __syncthreads();
  sum = red[0] + red[1] + red[2] + red[3];
  const float inv = 1.0f / sum;

  for (int m = t; m < 2048; m += 256) {
    float vs = 1.0f / fmaxf(sqrtf(vn2[b * 2048 + m]), 1e-12f);
    wgt[(size_t)row * 2048 + m] = (f16)(sl[m] * inv * vs);
  }
}

__global__ __launch_bounds__(256) void add_kernel(const float* __restrict__ x,
                                                  const float* __restrict__ fc,
                                                  float* __restrict__ out,
                                                  int n4) {
  int i = blockIdx.x * 256 + threadIdx.x;
  if (i >= n4) return;
  fv4 v = ((const fv4*)x)[i];
  int e = i * 4;
#pragma unroll
  for (int j = 0; j < 4; ++j) v[j] += fc[(e + j) / 49];
  ((fv4*)out)[i] = v;
}

// ---------------------------------------------------------------- launch
extern "C" void kernel_launch(void* const* d_in, const int* in_sizes, int n_in,
                              void* d_out, int out_size, void* d_ws,
                              size_t ws_size, hipStream_t stream) {
  (void)in_sizes; (void)n_in; (void)out_size; (void)ws_size;
  const float* x = (const float*)d_in[0];
  const float* xc = (const float*)d_in[1];
  const int* nvp = (const int*)d_in[2];
  const float* qW = (const float*)d_in[3];
  const float* qB = (const float*)d_in[4];
  const float* qG = (const float*)d_in[5];
  const float* qBe = (const float*)d_in[6];
  const float* qM = (const float*)d_in[7];
  const float* qV = (const float*)d_in[8];
  const float* kW = (const float*)d_in[9];
  const float* kB = (const float*)d_in[10];
  const float* kG = (const float*)d_in[11];
  const float* kBe = (const float*)d_in[12];
  const float* kM = (const float*)d_in[13];
  const float* kV = (const float*)d_in[14];
  const float* vW = (const float*)d_in[15];
  const float* vB = (const float*)d_in[16];
  const float* vG = (const float*)d_in[17];
  const float* vBe = (const float*)d_in[18];
  const float* vM = (const float*)d_in[19];
  const float* vV = (const float*)d_in[20];
  const float* fW = (const float*)d_in[21];
  const float* fB = (const float*)d_in[22];
  const float* fG = (const float*)d_in[23];
  const float* fBe = (const float*)d_in[24];
  const float* fM = (const float*)d_in[25];
  const float* fV = (const float*)d_in[26];
  float* out = (float*)d_out;

  const int NRq = 512;
  const int NRc = 16384;
  const int Dd = 1024, Cc = 2048, D1 = 2048, D2 = 2048, Mm = 2048;

  char* p = (char*)d_ws;
  auto take = [&](size_t bytes) -> char* {
    char* r = p;
    p += (bytes + 255) & ~(size_t)255;
    return r;
  };
  f16* xch = (f16*)take((size_t)NRc * Cc * 2);
  f16* kh = (f16*)take((size_t)NRc * D1 * 2);
  f16* vT = (f16*)take((size_t)NRc * D2 * 2);  // [b][d][m] transposed values
  f16* qWh = (f16*)take((size_t)D1 * Dd * 2);
  f16* kWh = (f16*)take((size_t)D1 * Cc * 2);
  f16* vWh = (f16*)take((size_t)D2 * Cc * 2);
  f16* fWh = (f16*)take((size_t)Dd * D2 * 2);
  f16* Aph = (f16*)take((size_t)NRq * Dd * 2);
  f16* qh = (f16*)take((size_t)NRq * D1 * 2);
  float* norms = (float*)take((size_t)(NRq + 2 * NRc) * 4);
  float* qn2 = norms;
  float* kn2 = norms + NRq;
  float* vn2 = norms + NRq + NRc;
  float* raw = (float*)take((size_t)NRq * Mm * 4);
  f16* wgt = (f16*)take((size_t)NRq * Mm * 2);
  f16* wvh = (f16*)take((size_t)NRq * D2 * 2);
  float* fctx = (float*)take((size_t)NRq * Dd * 4);

  // all fp32->fp16 conversions in one kernel
  const int n4_0 = NRc * Cc / 4;           // xc
  const int n4_1 = D1 * Dd / 4;            // qW
  const int n4_2 = D1 * Cc / 4;            // kW
  const int n4_3 = D2 * Cc / 4;            // vW
  const int n4_4 = Dd * D2 / 4;            // fW
  const int cum0 = n4_0, cum1 = cum0 + n4_1, cum2 = cum1 + n4_2,
            cum3 = cum2 + n4_3, cum4 = cum3 + n4_4;
  cvt_multi_kernel<<<dim3((cum4 + 255) / 256), 256, 0, stream>>>(
      xc, xch, qW, qWh, kW, kWh, vW, vWh, fW, fWh, cum0, cum1, cum2, cum3,
      cum4);
  pool_kernel<<<dim3(512), 256, 0, stream>>>(x, Aph);
  hipMemsetAsync(norms, 0, (size_t)(NRq + 2 * NRc) * 4, stream);

  // Q: 128^2 kernel (BM=32: 256 blocks), single-pass fp16
  gemm_kernel<32, 128, EPI_HALF_NORM>
      <<<dim3(D1 / 128, NRq / 32, 1), 256, 0, stream>>>(
          Aph, qWh, NRq, D1, Dd, 0, 0, 0, nullptr, qh, qB, qG, qBe, qM, qV,
          qn2);
  // K: 8-phase 256^2, single-pass fp16
  gemm8_kernel<EPI_HALF_NORM>
      <<<dim3((NRc / 256) * (D1 / 256)), 512, 0, stream>>>(
          xch, kWh, D1, Cc, D1 / 256, kh, kB, kG, kBe, kM, kV, kn2);
  // V^T: 8-phase 256^2, A=vW rows=d2, B=xc rows=items -> C[d][b*m]
  gemm8_kernel<EPI_HALF_NORM_T>
      <<<dim3((D2 / 256) * (NRc / 256)), 512, 0, stream>>>(
          vWh, xch, NRc, Cc, NRc / 256, vT, vB, vG, vBe, vM, vV, vn2);
  // sim (batched): single-pass fp16 -> raw fp32 (BM=32: 256 blocks)
  gemm_kernel<32, 128, EPI_RAW><<<dim3(Mm / 128, 2, 8), 256, 0, stream>>>(
      qh, kh, 64, Mm, D1, (long long)64 * D1, (long long)Mm * D1,
      (long long)64 * Mm, raw, nullptr, nullptr, nullptr, nullptr, nullptr,
      nullptr, nullptr);
  softmax_kernel<<<dim3(64, 8), 256, 0, stream>>>(raw, qn2, kn2, vn2, nvp, wgt);
  gemm_kernel<32, 128, EPI_HALF><<<dim3(D2 / 128, 2, 8), 256, 0, stream>>>(
      wgt, vT, 64, D2, Mm, (long long)64 * Mm, (long long)D2 * Mm,
      (long long)64 * D2, nullptr, wvh, nullptr, nullptr, nullptr, nullptr,
      nullptr, nullptr);
  // f: BM=32 -> 128 blocks
  gemm_kernel<32, 128, EPI_BN_F32>
      <<<dim3(Dd / 128, NRq / 32, 1), 256, 0, stream>>>(
          wvh, fWh, NRq, Dd, D2, 0, 0, 0, fctx, nullptr, fB, fG, fBe, fM, fV,
          nullptr);
  add_kernel<<<dim3(25690112 / 4 / 256), 256, 0, stream>>>(x, fctx, out,
                                                           25690112 / 4);
}